// Round 11
// baseline (88.222 us; speedup 1.0000x reference)
//
#include <hip/hip_runtime.h>
#include <hip/hip_bf16.h>

#define S_LEN  1024
#define BATCH  4
#define DMODEL 1024
#define NHEAD  16
#define DHEAD  64
#define NROWS  (S_LEN*BATCH)   // 4096

typedef __bf16 bf16;
typedef __bf16 bf16x2 __attribute__((ext_vector_type(2)));
typedef __bf16 bf16x4 __attribute__((ext_vector_type(4)));
typedef __bf16 bf16x8 __attribute__((ext_vector_type(8)));
typedef float  f32x4  __attribute__((ext_vector_type(4)));
typedef float  f32x16 __attribute__((ext_vector_type(16)));

#define AS1 __attribute__((address_space(1)))
#define AS3 __attribute__((address_space(3)))

#define QSCALE  0.18033688011112042f   // 0.125 * log2(e)

__device__ __forceinline__ void gload16(const bf16* g, bf16* l) {
  __builtin_amdgcn_global_load_lds((const AS1 void*)g, (AS3 void*)l, 16, 0, 0);
}

__device__ __forceinline__ float fast_exp2(float x) {
#if __has_builtin(__builtin_amdgcn_exp2f)
  return __builtin_amdgcn_exp2f(x);
#else
  return exp2f(x);
#endif
}

// ---------------- fused fp32 -> bf16 convert + mask bitmask ----------------
__global__ __launch_bounds__(256) void cvt_all(
    const float* __restrict__ hs, const float* __restrict__ wq,
    const float* __restrict__ wk, const float* __restrict__ wv,
    const float* __restrict__ mask,
    bf16* __restrict__ Xb, bf16* __restrict__ Wb,
    unsigned long long* __restrict__ mbits)
{
  const int b = blockIdx.x;
  if (b == 3584) {   // mask -> per-tile 64-bit masked-position bitmask
    const int wv = threadIdx.x >> 6, lane = threadIdx.x & 63;
    #pragma unroll
    for (int t16 = 0; t16 < 16; ++t16) {
      const float v = mask[(size_t)wv*S_LEN + t16*64 + lane];
      const unsigned long long bal = __ballot(v < -1000.f);
      if (lane == 0) mbits[wv*16 + t16] = bal;
    }
    return;
  }
  const float* src; bf16* dst; int i;
  if (b < 2048)      { src = hs; dst = Xb;                           i = b*256        + threadIdx.x; }
  else if (b < 2560) { src = wq; dst = Wb;                           i = (b-2048)*256 + threadIdx.x; }
  else if (b < 3072) { src = wk; dst = Wb + (size_t)DMODEL*DMODEL;   i = (b-2560)*256 + threadIdx.x; }
  else               { src = wv; dst = Wb + (size_t)2*DMODEL*DMODEL; i = (b-3072)*256 + threadIdx.x; }
  const float4* s4 = (const float4*)src;
  float4 a = s4[2*i], c = s4[2*i+1];
  bf16x8 o;
  o[0]=(bf16)a.x; o[1]=(bf16)a.y; o[2]=(bf16)a.z; o[3]=(bf16)a.w;
  o[4]=(bf16)c.x; o[5]=(bf16)c.y; o[6]=(bf16)c.z; o[7]=(bf16)c.w;
  ((bf16x8*)dst)[i] = o;
}

// ---------------- fused QKV GEMM, m97 structure (unchanged) ----------------
#define BM 128
#define BN 128
#define BK 32

__global__ __launch_bounds__(256) void qkv_gemm(
    const bf16* __restrict__ X, const bf16* __restrict__ Wcat,
    const float* __restrict__ bq, const float* __restrict__ bk, const float* __restrict__ bv,
    bf16* __restrict__ Qo, bf16* __restrict__ Ko, bf16* __restrict__ Vo)
{
  __shared__ __align__(16) bf16 As[BM*BK];
  __shared__ __align__(16) bf16 Bs[BN*BK];

  const int tid  = threadIdx.x;
  const int row0 = blockIdx.x * BM;
  const int col0 = blockIdx.y * BN;
  const int wsel = col0 >> 10;
  const int coln = col0 & 1023;

  const int wv   = tid >> 6;
  const int lane = tid & 63;
  const int lg   = lane >> 4;
  const int lr   = lane & 15;
  const int wr   = (wv >> 1) << 6;
  const int wc   = (wv & 1) << 6;

  const int c0 = tid, c1 = tid + 256;
  const size_t gA0 = (size_t)(row0 + (c0>>2))*DMODEL + (size_t)((c0&3)<<3);
  const size_t gA1 = (size_t)(row0 + (c1>>2))*DMODEL + (size_t)((c1&3)<<3);
  const size_t gB0 = (size_t)(col0 + (c0>>2))*DMODEL + (size_t)((c0&3)<<3);
  const size_t gB1 = (size_t)(col0 + (c1>>2))*DMODEL + (size_t)((c1&3)<<3);
  const int wb = (tid >> 6) << 6;
  bf16* lA0 = As + (size_t)wb*8;
  bf16* lA1 = As + (size_t)(wb+256)*8;
  bf16* lB0 = Bs + (size_t)wb*8;
  bf16* lB1 = Bs + (size_t)(wb+256)*8;

  f32x4 acc[4][4];
  #pragma unroll
  for (int mi=0; mi<4; ++mi)
    #pragma unroll
    for (int ni=0; ni<4; ++ni)
      acc[mi][ni] = (f32x4){0.f,0.f,0.f,0.f};

  for (int k0 = 0; k0 < DMODEL; k0 += BK) {
    __syncthreads();
    gload16(X    + gA0 + k0, lA0);
    gload16(X    + gA1 + k0, lA1);
    gload16(Wcat + gB0 + k0, lB0);
    gload16(Wcat + gB1 + k0, lB1);
    __syncthreads();

    bf16x8 af[4], bfr[4];
    #pragma unroll
    for (int mi=0; mi<4; ++mi)
      af[mi] = *(const bf16x8*)&As[(wr + mi*16 + lr)*BK + lg*8];
    #pragma unroll
    for (int ni=0; ni<4; ++ni)
      bfr[ni] = *(const bf16x8*)&Bs[(wc + ni*16 + lr)*BK + lg*8];

    #pragma unroll
    for (int mi=0; mi<4; ++mi)
      #pragma unroll
      for (int ni=0; ni<4; ++ni)
        acc[mi][ni] = __builtin_amdgcn_mfma_f32_16x16x32_bf16(af[mi], bfr[ni], acc[mi][ni], 0, 0, 0);
  }

  const float* bias = (wsel==0) ? bq : ((wsel==1) ? bk : bv);
  bf16* Out = (wsel==0) ? Qo : ((wsel==1) ? Ko : Vo);
  const float oscale = (wsel==0) ? QSCALE : 1.0f;

  #pragma unroll
  for (int ni=0; ni<4; ++ni) {
    const int co = coln + wc + ni*16 + lr;
    const float bias_v = bias[co];
    const int h  = co >> 6;
    const int dh = co & 63;
    #pragma unroll
    for (int mi=0; mi<4; ++mi) {
      #pragma unroll
      for (int p=0; p<4; ++p) {
        const int gr = row0 + wr + mi*16 + lg*4 + p;
        const int s_ = gr >> 2;
        const int b_ = gr & 3;
        Out[((size_t)(b_*NHEAD + h)*S_LEN + s_)*DHEAD + dh] = (bf16)((acc[mi][ni][p] + bias_v) * oscale);
      }
    }
  }
}

// ---------------- V transpose: [B][H][S][64] -> [B][H][64][S] (done once) ----------------
__global__ __launch_bounds__(256) void vtrans(const bf16* __restrict__ V, bf16* __restrict__ VT)
{
  __shared__ bf16 Ts[64][72];
  const int bh = blockIdx.x;
  const int s0 = blockIdx.y * 64;
  const int tid = threadIdx.x;
  const int r = tid >> 2, c = (tid & 3) << 4;
  const bf16* src = V + ((size_t)bh*S_LEN + s0 + r)*DHEAD + c;
  *(bf16x8*)&Ts[r][c]     = *(const bf16x8*)src;
  *(bf16x8*)&Ts[r][c + 8] = *(const bf16x8*)(src + 8);
  __syncthreads();
  const int d = tid >> 2, sc = (tid & 3) << 4;
  bf16x8 o0, o1;
  #pragma unroll
  for (int i=0;i<8;++i) { o0[i] = Ts[sc+i][d]; o1[i] = Ts[sc+8+i][d]; }
  bf16* dst = VT + ((size_t)bh*DHEAD + d)*S_LEN + s0 + sc;
  *(bf16x8*)dst       = o0;
  *(bf16x8*)(dst + 8) = o1;
}

// ================= ATTENTION CORE (shared body via macro-free duplication) =================
// r10-verified body: 4 waves x 32 q, QBLK=128, KVB=64, dbuf, DMA staging with
// pre-swizzled source, bitmask mask, zero-shuffle P, 32x32 MFMA.
#define QBLK 128
#define KVB  64
#define LSWK(row, chunk) (((row)<<6) + ((((chunk) ^ ((row)&7)))<<3))

// ---- split version: grid 1024 (XCD-chunked); sp in {0,1} sweeps 8 tiles; bf16 partials ----
__global__ __launch_bounds__(256, 4) void attn_split(
    const bf16* __restrict__ Q, const bf16* __restrict__ K, const bf16* __restrict__ VT,
    const unsigned long long* __restrict__ mbits,
    bf16* __restrict__ Pc, float* __restrict__ Pl)
{
  __shared__ __align__(16) bf16 KsBuf[2][KVB*64];
  __shared__ __align__(16) bf16 VtBuf[2][64*KVB];

  // XCD-chunked decode: xcd = id&7 serves bh in [xcd*8, xcd*8+8)
  const int id   = blockIdx.x;
  const int xcd  = id & 7;
  const int rank = id >> 3;            // 0..127
  const int bh   = xcd*8 + (rank >> 4);
  const int r2   = rank & 15;
  const int qb   = r2 >> 1;
  const int sp   = r2 & 1;

  const int b_   = bh >> 4;
  const int tid  = threadIdx.x;
  const int wv   = tid >> 6;
  const int lane = tid & 63;
  const int l31  = lane & 31;
  const int hh   = lane >> 5;
  const int q0   = qb * QBLK;

  const bf16* Qp = Q + ((size_t)bh*S_LEN + q0 + wv*32 + l31)*DHEAD;
  bf16x8 qb_[4];
  #pragma unroll
  for (int dk=0; dk<4; ++dk) qb_[dk] = *(const bf16x8*)&Qp[dk*16 + hh*8];

  const bf16* Kb  = K  + (size_t)bh*S_LEN*DHEAD;
  const bf16* VTb = VT + (size_t)bh*DHEAD*S_LEN;
  const unsigned long long* mbp = mbits + (size_t)b_*16 + sp*8;

  const int g0   = wv*64 + lane;
  const int row0_= g0 >> 3, cs0 = g0 & 7;
  const int ch0  = cs0 ^ (row0_ & 7);
  const size_t koff0 = (size_t)row0_*DHEAD + ch0*8 + (size_t)sp*8*KVB*DHEAD;
  const size_t koff1 = koff0 + (size_t)32*DHEAD;
  const size_t voff0 = (size_t)row0_*S_LEN + ch0*8 + (size_t)sp*8*KVB;
  const size_t voff1 = voff0 + (size_t)32*S_LEN;
  const int wdst0 = wv*512, wdst1 = wv*512 + 2048;

  gload16(Kb  + koff0,  (bf16*)KsBuf[0] + wdst0);
  gload16(Kb  + koff1,  (bf16*)KsBuf[0] + wdst1);
  gload16(VTb + voff0,  (bf16*)VtBuf[0] + wdst0);
  gload16(VTb + voff1,  (bf16*)VtBuf[0] + wdst1);
  __syncthreads();

  f32x16 ctx[2];
  ctx[0] = (f32x16)0.f; ctx[1] = (f32x16)0.f;
  float lsum = 0.f;

  for (int t = 0; t < 8; ++t) {
    const bf16* Kc = KsBuf[t & 1];
    const bf16* Vc = VtBuf[t & 1];

    if (t < 7) {
      const size_t nk = (size_t)(t+1)*KVB*DHEAD;
      const size_t nv = (size_t)(t+1)*KVB;
      bf16* kn = (bf16*)KsBuf[(t+1) & 1];
      bf16* vn = (bf16*)VtBuf[(t+1) & 1];
      gload16(Kb  + nk + koff0, kn + wdst0);
      gload16(Kb  + nk + koff1, kn + wdst1);
      gload16(VTb + nv + voff0, vn + wdst0);
      gload16(VTb + nv + voff1, vn + wdst1);
    }

    const unsigned long long mt = mbp[t];

    #pragma unroll
    for (int t2=0; t2<2; ++t2) {
      f32x16 sacc = (f32x16)0.f;
      const int row = t2*32 + l31;
      __builtin_amdgcn_s_setprio(1);
      #pragma unroll
      for (int dk=0; dk<4; ++dk) {
        bf16x8 ka = *(const bf16x8*)&Kc[LSWK(row, dk*2 + hh)];
        sacc = __builtin_amdgcn_mfma_f32_32x32x16_bf16(ka, qb_[dk], sacc, 0,0,0);
      }
      __builtin_amdgcn_s_setprio(0);

      const unsigned int mw = (unsigned int)(mt >> (t2*32 + 4*hh));
      float pe[16];
      #pragma unroll
      for (int e=0; e<16; ++e) {
        const float ex = fast_exp2(sacc[e]);
        pe[e] = ((mw >> ((e&3) + 8*(e>>2))) & 1u) ? 0.f : ex;
        lsum += pe[e];
      }
      bf16x8 pf[2];
      {
        union { bf16x2 h2[8]; bf16x8 v[2]; } u;
        #pragma unroll
        for (int j=0; j<8; ++j) { bf16x2 p2; p2[0]=(bf16)pe[2*j]; p2[1]=(bf16)pe[2*j+1]; u.h2[j]=p2; }
        pf[0] = u.v[0]; pf[1] = u.v[1];
      }

      __builtin_amdgcn_s_setprio(1);
      #pragma unroll
      for (int nt=0; nt<2; ++nt) {
        const int drow = nt*32 + l31;
        const int dbase = (drow<<6) + 4*hh;
        const int dsw = (drow&7);
        #pragma unroll
        for (int kk=0; kk<2; ++kk) {
          const int lc = t2*4 + kk*2;
          bf16x4 lo = *(const bf16x4*)&Vc[dbase + (((lc  ) ^ dsw)<<3)];
          bf16x4 hi = *(const bf16x4*)&Vc[dbase + (((lc+1) ^ dsw)<<3)];
          bf16x8 vb;
          #pragma unroll
          for (int j=0; j<4; ++j) { vb[j]=lo[j]; vb[4+j]=hi[j]; }
          ctx[nt] = __builtin_amdgcn_mfma_f32_32x32x16_bf16(pf[kk], vb, ctx[nt], 0,0,0);
        }
      }
      __builtin_amdgcn_s_setprio(0);
    }

    __syncthreads();
  }

  // ---- write unnormalized partials: ctx (bf16) + lsum (f32) ----
  const float tot = lsum + __shfl_xor(lsum, 32);
  if (lane < 32) Pl[(size_t)(sp*64 + bh)*S_LEN + q0 + wv*32 + l31] = tot;

  bf16* pc = Pc + ((size_t)(sp*64 + bh)*S_LEN + q0 + wv*32)*DHEAD + l31;
  #pragma unroll
  for (int e=0; e<16; ++e) {
    const int qe = (e&3) + 8*(e>>2) + 4*hh;
    bf16* pq = pc + (size_t)qe*DHEAD;
    pq[0]  = (bf16)ctx[0][e];
    pq[32] = (bf16)ctx[1][e];
  }
}

// ---- combine: out = (A0+A1)/(l0+l1), [bh][q][d] -> out[s][b][h*64+d] ----
__global__ __launch_bounds__(256) void attn_combine(
    const bf16* __restrict__ Pc, const float* __restrict__ Pl, float* __restrict__ out)
{
  const int bh = blockIdx.x;
  const int b_ = bh >> 4;
  const int h_ = bh & 15;
  const int tid = threadIdx.x;
  const int q  = blockIdx.y*128 + (tid >> 1);
  const int d0 = (tid & 1) << 5;

  const size_t i0 = ((size_t)bh*S_LEN + q)*DHEAD + d0;
  const size_t i1 = ((size_t)(64 + bh)*S_LEN + q)*DHEAD + d0;
  bf16x8 a0[4], a1[4];
  #pragma unroll
  for (int j=0; j<4; ++j) { a0[j] = *(const bf16x8*)&Pc[i0 + j*8]; a1[j] = *(const bf16x8*)&Pc[i1 + j*8]; }
  const float l0 = Pl[(size_t)bh*S_LEN + q];
  const float l1 = Pl[(size_t)(64 + bh)*S_LEN + q];
  const float inv = 1.f / (l0 + l1);

  float* op = out + ((size_t)q*BATCH + b_)*DMODEL + h_*DHEAD + d0;
  #pragma unroll
  for (int j=0; j<4; ++j) {
    f32x4 o0, o1;
    #pragma unroll
    for (int k=0; k<4; ++k) {
      o0[k] = ((float)a0[j][k]   + (float)a1[j][k])   * inv;
      o1[k] = ((float)a0[j][4+k] + (float)a1[j][4+k]) * inv;
    }
    *(f32x4*)&op[j*8]     = o0;
    *(f32x4*)&op[j*8 + 4] = o1;
  }
}

// ---- fallback: r10 single-pass attention (unchanged, used if ws too small) ----
__global__ __launch_bounds__(256, 4) void attn_mfma(
    const bf16* __restrict__ Q, const bf16* __restrict__ K, const bf16* __restrict__ VT,
    const unsigned long long* __restrict__ mbits, float* __restrict__ out)
{
  __shared__ __align__(16) bf16 KsBuf[2][KVB*64];
  __shared__ __align__(16) bf16 VtBuf[2][64*KVB];
  __shared__ float Linv[4][32];

  const int bh   = blockIdx.x;
  const int b_   = bh >> 4;
  const int h_   = bh & 15;
  const int tid  = threadIdx.x;
  const int wv   = tid >> 6;
  const int lane = tid & 63;
  const int l31  = lane & 31;
  const int hh   = lane >> 5;
  const int q0   = blockIdx.y * QBLK;

  const bf16* Qp = Q + ((size_t)bh*S_LEN + q0 + wv*32 + l31)*DHEAD;
  bf16x8 qb[4];
  #pragma unroll
  for (int dk=0; dk<4; ++dk) qb[dk] = *(const bf16x8*)&Qp[dk*16 + hh*8];

  const bf16* Kb  = K  + (size_t)bh*S_LEN*DHEAD;
  const bf16* VTb = VT + (size_t)bh*DHEAD*S_LEN;
  const unsigned long long* mbp = mbits + (size_t)b_*16;

  const int g0   = wv*64 + lane;
  const int row0_= g0 >> 3, cs0 = g0 & 7;
  const int ch0  = cs0 ^ (row0_ & 7);
  const size_t koff0 = (size_t)row0_*DHEAD + ch0*8;
  const size_t koff1 = koff0 + (size_t)32*DHEAD;
  const size_t voff0 = (size_t)row0_*S_LEN + ch0*8;
  const size_t voff1 = voff0 + (size_t)32*S_LEN;
  const int wdst0 = wv*512, wdst1 = wv*512 + 2048;

  gload16(Kb  + koff0,  (bf16*)KsBuf[0] + wdst0);
  gload16(Kb  + koff1,  (bf16*)KsBuf[0] + wdst1);
  gload16(VTb + voff0,  (bf16*)VtBuf[0] + wdst0);
  gload16(VTb + voff1,  (bf16*)VtBuf[0] + wdst1);
  __syncthreads();

  f32x16 ctx[2];
  ctx[0] = (f32x16)0.f; ctx[1] = (f32x16)0.f;
  float lsum = 0.f;

  for (int t = 0; t < 16; ++t) {
    const bf16* Kc = KsBuf[t & 1];
    const bf16* Vc = VtBuf[t & 1];
    if (t < 15) {
      const size_t nk = (size_t)(t+1)*KVB*DHEAD;
      const size_t nv = (size_t)(t+1)*KVB;
      bf16* kn = (bf16*)KsBuf[(t+1) & 1];
      bf16* vn = (bf16*)VtBuf[(t+1) & 1];
      gload16(Kb  + nk + koff0, kn + wdst0);
      gload16(Kb  + nk + koff1, kn + wdst1);
      gload16(VTb + nv + voff0, vn + wdst0);
      gload16(VTb + nv + voff1, vn + wdst1);
    }
    const unsigned long long mt = mbp[t];
    #pragma unroll
    for (int t2=0; t2<2; ++t2) {
      f32x16 sacc = (f32x16)0.f;
      const int row = t2*32 + l31;
      __builtin_amdgcn_s_setprio(1);
      #pragma unroll
      for (int dk=0; dk<4; ++dk) {
        bf16x8 ka = *(const bf16x8*)&Kc[LSWK(row, dk*2 + hh)];
        sacc = __builtin_amdgcn_mfma_f32_32x32x16_bf16(ka, qb[dk], sacc, 0,0,0);
      }
      __builtin_amdgcn_s_setprio(0);
      const unsigned int mw = (unsigned int)(mt >> (t2*32 + 4*hh));
      float pe[16];
      #pragma unroll
      for (int e=0; e<16; ++e) {
        const float ex = fast_exp2(sacc[e]);
        pe[e] = ((mw >> ((e&3) + 8*(e>>2))) & 1u) ? 0.f : ex;
        lsum += pe[e];
      }
      bf16x8 pf[2];
      {
        union { bf16x2 h2[8]; bf16x8 v[2]; } u;
        #pragma unroll
        for (int j=0; j<8; ++j) { bf16x2 p2; p2[0]=(bf16)pe[2*j]; p2[1]=(bf16)pe[2*j+1]; u.h2[j]=p2; }
        pf[0] = u.v[0]; pf[1] = u.v[1];
      }
      __builtin_amdgcn_s_setprio(1);
      #pragma unroll
      for (int nt=0; nt<2; ++nt) {
        const int drow = nt*32 + l31;
        const int dbase = (drow<<6) + 4*hh;
        const int dsw = (drow&7);
        #pragma unroll
        for (int kk=0; kk<2; ++kk) {
          const int lc = t2*4 + kk*2;
          bf16x4 lo = *(const bf16x4*)&Vc[dbase + (((lc  ) ^ dsw)<<3)];
          bf16x4 hi = *(const bf16x4*)&Vc[dbase + (((lc+1) ^ dsw)<<3)];
          bf16x8 vb;
          #pragma unroll
          for (int j=0; j<4; ++j) { vb[j]=lo[j]; vb[4+j]=hi[j]; }
          ctx[nt] = __builtin_amdgcn_mfma_f32_32x32x16_bf16(pf[kk], vb, ctx[nt], 0,0,0);
        }
      }
      __builtin_amdgcn_s_setprio(0);
    }
    __syncthreads();
  }

  const float tot = lsum + __shfl_xor(lsum, 32);
  if (lane < 32) Linv[wv][l31] = 1.f / tot;
  f32x4 inv4[4];
  #pragma unroll
  for (int g4=0; g4<4; ++g4) inv4[g4] = *(const f32x4*)&Linv[wv][8*g4 + 4*hh];

  float* op = out + ((size_t)(q0 + wv*32)*BATCH + b_)*DMODEL + h_*DHEAD + l31;
  #pragma unroll
  for (int e=0; e<16; ++e) {
    const int qe = (e&3) + 8*(e>>2) + 4*hh;
    const float inv = inv4[e>>2][e&3];
    float* oq = op + (size_t)qe*BATCH*DMODEL;
    oq[0]  = ctx[0][e] * inv;
    oq[32] = ctx[1][e] * inv;
  }
}

// ---------------- launch ----------------
extern "C" void kernel_launch(void* const* d_in, const int* in_sizes, int n_in,
                              void* d_out, int out_size, void* d_ws, size_t ws_size,
                              hipStream_t stream) {
  const float* hs   = (const float*)d_in[0];
  const float* mask = (const float*)d_in[1];
  const float* Wq   = (const float*)d_in[2];
  const float* bq   = (const float*)d_in[3];
  const float* Wk   = (const float*)d_in[4];
  const float* bk   = (const float*)d_in[5];
  const float* Wv   = (const float*)d_in[6];
  const float* bv   = (const float*)d_in[7];
  float* out = (float*)d_out;

  char* ws = (char*)d_ws;
  bf16* Xb = (bf16*)ws;                               // 8 MB; reused as VT after gemm
  bf16* Wb = Xb + (size_t)NROWS*DMODEL;               // 6 MB
  bf16* Qw = Wb + (size_t)3*DMODEL*DMODEL;            // 8 MB
  bf16* Kw = Qw + (size_t)NROWS*DMODEL;               // 8 MB
  bf16* Vw = Kw + (size_t)NROWS*DMODEL;               // 8 MB
  unsigned long long* Mb = (unsigned long long*)(Vw + (size_t)NROWS*DMODEL);  // 512 B
  bf16*  Pc = (bf16*)((char*)Mb + 4096);              // 16 MB: [2][64][1024][64] bf16
  float* Pl = (float*)(Pc + (size_t)2*64*S_LEN*DHEAD);// 512 KB
  bf16* VTw = Xb;

  const size_t need = ((char*)(Pl + (size_t)2*64*S_LEN) - ws);

  cvt_all<<<3585, 256, 0, stream>>>(hs, Wq, Wk, Wv, mask, Xb, Wb, Mb);

  qkv_gemm<<<dim3(NROWS/BM, 3*DMODEL/BN), 256, 0, stream>>>(Xb, Wb, bq, bk, bv, Qw, Kw, Vw);

  vtrans<<<dim3(BATCH*NHEAD, S_LEN/64), 256, 0, stream>>>(Vw, VTw);

  if (ws_size >= need) {
    attn_split<<<1024, 256, 0, stream>>>(Qw, Kw, VTw, Mb, Pc, Pl);
    attn_combine<<<dim3(BATCH*NHEAD, S_LEN/128), 256, 0, stream>>>(Pc, Pl, out);
  } else {
    attn_mfma<<<dim3(BATCH*NHEAD, S_LEN/QBLK), 256, 0, stream>>>(Qw, Kw, VTw, Mb, out);
  }
}

// Round 12
// 82.994 us; speedup vs baseline: 1.0630x; 1.0630x over previous
//
#include <hip/hip_runtime.h>
#include <hip/hip_bf16.h>

#define S_LEN  1024
#define BATCH  4
#define DMODEL 1024
#define NHEAD  16
#define DHEAD  64
#define NROWS  (S_LEN*BATCH)   // 4096

typedef __bf16 bf16;
typedef __bf16 bf16x2 __attribute__((ext_vector_type(2)));
typedef __bf16 bf16x4 __attribute__((ext_vector_type(4)));
typedef __bf16 bf16x8 __attribute__((ext_vector_type(8)));
typedef float  f32x4  __attribute__((ext_vector_type(4)));
typedef float  f32x16 __attribute__((ext_vector_type(16)));

#define AS1 __attribute__((address_space(1)))
#define AS3 __attribute__((address_space(3)))

#define QSCALE  0.18033688011112042f   // 0.125 * log2(e)

__device__ __forceinline__ void gload16(const bf16* g, bf16* l) {
  __builtin_amdgcn_global_load_lds((const AS1 void*)g, (AS3 void*)l, 16, 0, 0);
}

__device__ __forceinline__ float fast_exp2(float x) {
#if __has_builtin(__builtin_amdgcn_exp2f)
  return __builtin_amdgcn_exp2f(x);
#else
  return exp2f(x);
#endif
}

// ---------------- fused fp32 -> bf16 convert + mask bitmask ----------------
__global__ __launch_bounds__(256) void cvt_all(
    const float* __restrict__ hs, const float* __restrict__ wq,
    const float* __restrict__ wk, const float* __restrict__ wv,
    const float* __restrict__ mask,
    bf16* __restrict__ Xb, bf16* __restrict__ Wb,
    unsigned long long* __restrict__ mbits)
{
  const int b = blockIdx.x;
  if (b == 3584) {   // mask -> per-tile 64-bit masked-position bitmask
    const int wv = threadIdx.x >> 6, lane = threadIdx.x & 63;
    #pragma unroll
    for (int t16 = 0; t16 < 16; ++t16) {
      const float v = mask[(size_t)wv*S_LEN + t16*64 + lane];
      const unsigned long long bal = __ballot(v < -1000.f);
      if (lane == 0) mbits[wv*16 + t16] = bal;
    }
    return;
  }
  const float* src; bf16* dst; int i;
  if (b < 2048)      { src = hs; dst = Xb;                           i = b*256        + threadIdx.x; }
  else if (b < 2560) { src = wq; dst = Wb;                           i = (b-2048)*256 + threadIdx.x; }
  else if (b < 3072) { src = wk; dst = Wb + (size_t)DMODEL*DMODEL;   i = (b-2560)*256 + threadIdx.x; }
  else               { src = wv; dst = Wb + (size_t)2*DMODEL*DMODEL; i = (b-3072)*256 + threadIdx.x; }
  const float4* s4 = (const float4*)src;
  float4 a = s4[2*i], c = s4[2*i+1];
  bf16x8 o;
  o[0]=(bf16)a.x; o[1]=(bf16)a.y; o[2]=(bf16)a.z; o[3]=(bf16)a.w;
  o[4]=(bf16)c.x; o[5]=(bf16)c.y; o[6]=(bf16)c.z; o[7]=(bf16)c.w;
  ((bf16x8*)dst)[i] = o;
}

// ---------------- fused QKV GEMM: m97 structure, BK=64, conflict-free swizzle ----------------
// LDS image: granule (row, s) holds logical k-chunk s^(row&7)  (chunk = 8 bf16).
// gload source pre-applies the inverse; ds_read applies the same XOR -> 2-way max conflicts.
#define BM 128
#define BN 128
#define BK 64

__global__ __launch_bounds__(256) void qkv_gemm(
    const bf16* __restrict__ X, const bf16* __restrict__ Wcat,
    const float* __restrict__ bq, const float* __restrict__ bk, const float* __restrict__ bv,
    bf16* __restrict__ Qo, bf16* __restrict__ Ko, bf16* __restrict__ Vo)
{
  __shared__ __align__(16) bf16 As[BM*BK];   // 16 KB linear (row stride 64 elems)
  __shared__ __align__(16) bf16 Bs[BN*BK];   // 16 KB

  const int tid  = threadIdx.x;
  const int row0 = blockIdx.x * BM;
  const int col0 = blockIdx.y * BN;
  const int wsel = col0 >> 10;
  const int coln = col0 & 1023;

  const int wv   = tid >> 6;
  const int lane = tid & 63;
  const int lg   = lane >> 4;
  const int lr   = lane & 15;
  const int wr   = (wv >> 1) << 6;
  const int wc   = (wv & 1) << 6;

  // staging: 1024 granules(16B)/tile; thread covers granules tid + r*256 (r=0..3)
  // granule g: row=g>>3 (=rA+32r), slot=g&7 holds chunk (g&7)^(row&7); 32r==0 mod 8
  const int s_ = tid & 7;
  const int rA = tid >> 3;                 // 0..31
  const int ch = s_ ^ (rA & 7);            // source chunk (same for all r)
  const size_t gA = (size_t)(row0 + rA)*DMODEL + ch*8;
  const size_t gB = (size_t)(col0 + rA)*DMODEL + ch*8;
  const int wdst = wv*512;                 // elems: wave's granule-run base

  f32x4 acc[4][4];
  #pragma unroll
  for (int mi=0; mi<4; ++mi)
    #pragma unroll
    for (int ni=0; ni<4; ++ni)
      acc[mi][ni] = (f32x4){0.f,0.f,0.f,0.f};

  for (int k0 = 0; k0 < DMODEL; k0 += BK) {
    __syncthreads();
    #pragma unroll
    for (int r=0; r<4; ++r) {
      gload16(X    + gA + (size_t)(32*r)*DMODEL + k0, As + wdst + r*2048);
      gload16(Wcat + gB + (size_t)(32*r)*DMODEL + k0, Bs + wdst + r*2048);
    }
    __syncthreads();

    #pragma unroll
    for (int ks=0; ks<2; ++ks) {
      bf16x8 af[4], bfr[4];
      #pragma unroll
      for (int mi=0; mi<4; ++mi) {
        const int row = wr + mi*16 + lr;
        af[mi] = *(const bf16x8*)&As[row*BK + (((ks*4 + lg) ^ (lr & 7)) << 3)];
      }
      #pragma unroll
      for (int ni=0; ni<4; ++ni) {
        const int col = wc + ni*16 + lr;
        bfr[ni] = *(const bf16x8*)&Bs[col*BK + (((ks*4 + lg) ^ (lr & 7)) << 3)];
      }
      #pragma unroll
      for (int mi=0; mi<4; ++mi)
        #pragma unroll
        for (int ni=0; ni<4; ++ni)
          acc[mi][ni] = __builtin_amdgcn_mfma_f32_16x16x32_bf16(af[mi], bfr[ni], acc[mi][ni], 0, 0, 0);
    }
  }

  const float* bias = (wsel==0) ? bq : ((wsel==1) ? bk : bv);
  bf16* Out = (wsel==0) ? Qo : ((wsel==1) ? Ko : Vo);
  const float oscale = (wsel==0) ? QSCALE : 1.0f;

  #pragma unroll
  for (int ni=0; ni<4; ++ni) {
    const int co = coln + wc + ni*16 + lr;
    const float bias_v = bias[co];
    const int h  = co >> 6;
    const int dh = co & 63;
    #pragma unroll
    for (int mi=0; mi<4; ++mi) {
      #pragma unroll
      for (int p=0; p<4; ++p) {
        const int gr = row0 + wr + mi*16 + lg*4 + p;
        const int s2 = gr >> 2;
        const int b2 = gr & 3;
        Out[((size_t)(b2*NHEAD + h)*S_LEN + s2)*DHEAD + dh] = (bf16)((acc[mi][ni][p] + bias_v) * oscale);
      }
    }
  }
}

// ---------------- MFMA flash attention: r7 body (best known) + bitmask mask ----------------
// 4 waves x 32 q, QBLK=128, KVB=64, dbuf K/V, XOR chunk-swizzle, zero-shuffle P,
// swapped QK^T (D[t][q], q=lane&31), mask as 64-bit bitmask (p = bit ? 0 : exp2(s)).
#define QBLK 128
#define LSW(row, chunk) (((row)<<6) + ((((chunk) ^ ((row)&7)))<<3))

__global__ __launch_bounds__(256, 2) void attn_mfma(
    const bf16* __restrict__ Q, const bf16* __restrict__ K, const bf16* __restrict__ V,
    const unsigned long long* __restrict__ mbits, float* __restrict__ out)
{
  __shared__ __align__(16) bf16 Ks[2][64*64];   // 16 KB
  __shared__ __align__(16) bf16 Vt[2][64*64];   // 16 KB (V^T, swizzled)
  __shared__ float Linv[4][32];                 // 512 B

  const int bh   = blockIdx.x;
  const int b_   = bh >> 4;
  const int h_   = bh & 15;
  const int tid  = threadIdx.x;
  const int wv   = tid >> 6;             // 0..3
  const int lane = tid & 63;
  const int l31  = lane & 31;
  const int hh   = lane >> 5;            // 0/1
  const int q0   = blockIdx.y * QBLK;

  // ---- Q B-frags from global (pre-scaled by QSCALE in gemm): q = lane&31 ----
  const bf16* Qp = Q + ((size_t)bh*S_LEN + q0 + wv*32 + l31)*DHEAD;
  bf16x8 qb[4];
  #pragma unroll
  for (int dk=0; dk<4; ++dk) qb[dk] = *(const bf16x8*)&Qp[dk*16 + hh*8];

  const bf16* Kb = K + (size_t)bh*S_LEN*DHEAD;
  const bf16* Vb = V + (size_t)bh*S_LEN*DHEAD;
  const unsigned long long* mbp = mbits + (size_t)b_*16;

  // staging maps (256 threads)
  const int krow = tid >> 2, kch = tid & 3;   // K: row, chunks kch & kch+4
  const int vrow = tid & 63, vcb = tid >> 6;  // V: row=lane, 16 cols starting vcb*16

  // ---- prologue: stage tile 0 ----
  bf16x8 kr0 = *(const bf16x8*)&Kb[(size_t)krow*DHEAD + kch*8];
  bf16x8 kr1 = *(const bf16x8*)&Kb[(size_t)krow*DHEAD + kch*8 + 32];
  bf16x8 vr0 = *(const bf16x8*)&Vb[(size_t)vrow*DHEAD + vcb*16];
  bf16x8 vr1 = *(const bf16x8*)&Vb[(size_t)vrow*DHEAD + vcb*16 + 8];
  {
    *(bf16x8*)&Ks[0][LSW(krow, kch)]   = kr0;
    *(bf16x8*)&Ks[0][LSW(krow, kch+4)] = kr1;
    #pragma unroll
    for (int i=0;i<8;++i) {
      const int d0 = vcb*16 + i, d1 = d0 + 8;
      Vt[0][(d0<<6) + (((vrow>>3) ^ (d0&7))<<3) + (vrow&7)] = vr0[i];
      Vt[0][(d1<<6) + (((vrow>>3) ^ (d1&7))<<3) + (vrow&7)] = vr1[i];
    }
  }
  __syncthreads();

  f32x16 ctx[2];
  ctx[0] = (f32x16)0.f; ctx[1] = (f32x16)0.f;
  float lsum = 0.f;

  for (int t = 0; t < 16; ++t) {
    const bf16* Kc = Ks[t & 1];
    const bf16* Vc = Vt[t & 1];

    // issue next tile's global loads early
    if (t < 15) {
      const size_t nb = (size_t)(t+1)*64;
      kr0 = *(const bf16x8*)&Kb[(nb+krow)*DHEAD + kch*8];
      kr1 = *(const bf16x8*)&Kb[(nb+krow)*DHEAD + kch*8 + 32];
      vr0 = *(const bf16x8*)&Vb[(nb+vrow)*DHEAD + vcb*16];
      vr1 = *(const bf16x8*)&Vb[(nb+vrow)*DHEAD + vcb*16 + 8];
    }

    // ---- QK^T (swapped): D[t][q], 2 t-tiles of 32, contraction dh=64 ----
    f32x16 sacc[2];
    sacc[0] = (f32x16)0.f; sacc[1] = (f32x16)0.f;
    __builtin_amdgcn_s_setprio(1);
    #pragma unroll
    for (int tt=0; tt<2; ++tt) {
      const int row = tt*32 + l31;
      #pragma unroll
      for (int dk=0; dk<4; ++dk) {
        bf16x8 ka = *(const bf16x8*)&Kc[LSW(row, dk*2 + hh)];
        sacc[tt] = __builtin_amdgcn_mfma_f32_32x32x16_bf16(ka, qb[dk], sacc[tt], 0,0,0);
      }
    }
    __builtin_amdgcn_s_setprio(0);

    // ---- softmax: p = bit ? 0 : exp2(s); pack to PV A-frags in-lane ----
    const unsigned long long mt = mbp[t];
    bf16x8 pf[2][2];
    #pragma unroll
    for (int tt=0; tt<2; ++tt) {
      const unsigned int mw = (unsigned int)(mt >> (tt*32 + 4*hh));
      float pe[16];
      #pragma unroll
      for (int e=0; e<16; ++e) {
        const float ex = fast_exp2(sacc[tt][e]);
        pe[e] = ((mw >> ((e&3) + 8*(e>>2))) & 1u) ? 0.f : ex;
        lsum += pe[e];
      }
      union { bf16x2 h2[8]; bf16x8 v[2]; } u;
      #pragma unroll
      for (int j=0; j<8; ++j) { bf16x2 p2; p2[0]=(bf16)pe[2*j]; p2[1]=(bf16)pe[2*j+1]; u.h2[j]=p2; }
      pf[tt][0] = u.v[0]; pf[tt][1] = u.v[1];
    }

    // ---- PV: O[q][d] += P * V ; B-frags via slot->t map (2x b64 each) ----
    __builtin_amdgcn_s_setprio(1);
    #pragma unroll
    for (int nt=0; nt<2; ++nt) {
      const int drow = nt*32 + l31;
      const int dbase = (drow<<6) + 4*hh;
      const int dsw = (drow&7);
      #pragma unroll
      for (int tt=0; tt<2; ++tt) {
        #pragma unroll
        for (int kk=0; kk<2; ++kk) {
          const int lc = tt*4 + kk*2;
          bf16x4 lo = *(const bf16x4*)&Vc[dbase + (((lc  ) ^ dsw)<<3)];
          bf16x4 hi = *(const bf16x4*)&Vc[dbase + (((lc+1) ^ dsw)<<3)];
          bf16x8 vb;
          #pragma unroll
          for (int j=0; j<4; ++j) { vb[j]=lo[j]; vb[4+j]=hi[j]; }
          ctx[nt] = __builtin_amdgcn_mfma_f32_32x32x16_bf16(pf[tt][kk], vb, ctx[nt], 0,0,0);
        }
      }
    }
    __builtin_amdgcn_s_setprio(0);

    // ---- stage next tile into other buffer ----
    if (t < 15) {
      bf16* Kn = (bf16*)Ks[(t+1) & 1];
      bf16* Vn = (bf16*)Vt[(t+1) & 1];
      *(bf16x8*)&Kn[LSW(krow, kch)]   = kr0;
      *(bf16x8*)&Kn[LSW(krow, kch+4)] = kr1;
      #pragma unroll
      for (int i=0;i<8;++i) {
        const int d0 = vcb*16 + i, d1 = d0 + 8;
        Vn[(d0<<6) + (((vrow>>3) ^ (d0&7))<<3) + (vrow&7)] = vr0[i];
        Vn[(d1<<6) + (((vrow>>3) ^ (d1&7))<<3) + (vrow&7)] = vr1[i];
      }
    }
    __syncthreads();
  }

  // ---- lsum: partner-half add, distribute 1/lsum via per-wave LDS row ----
  const float tot = lsum + __shfl_xor(lsum, 32);
  if (lane < 32) Linv[wv][l31] = 1.f / tot;
  f32x4 inv4[4];
  #pragma unroll
  for (int g4=0; g4<4; ++g4) inv4[g4] = *(const f32x4*)&Linv[wv][8*g4 + 4*hh];

  // ---- write out: out[qg][b][h*64 + nt*32 + (lane&31)] ----
  float* op = out + ((size_t)(q0 + wv*32)*BATCH + b_)*DMODEL + h_*DHEAD + l31;
  #pragma unroll
  for (int e=0; e<16; ++e) {
    const int qe = (e&3) + 8*(e>>2) + 4*hh;
    const float inv = inv4[e>>2][e&3];
    float* oq = op + (size_t)qe*BATCH*DMODEL;
    oq[0]  = ctx[0][e] * inv;
    oq[32] = ctx[1][e] * inv;
  }
}

// ---------------- launch ----------------
extern "C" void kernel_launch(void* const* d_in, const int* in_sizes, int n_in,
                              void* d_out, int out_size, void* d_ws, size_t ws_size,
                              hipStream_t stream) {
  const float* hs   = (const float*)d_in[0];
  const float* mask = (const float*)d_in[1];
  const float* Wq   = (const float*)d_in[2];
  const float* bq   = (const float*)d_in[3];
  const float* Wk   = (const float*)d_in[4];
  const float* bk   = (const float*)d_in[5];
  const float* Wv   = (const float*)d_in[6];
  const float* bv   = (const float*)d_in[7];
  float* out = (float*)d_out;

  char* ws = (char*)d_ws;
  bf16* Xb = (bf16*)ws;                               // 8 MB
  bf16* Wb = Xb + (size_t)NROWS*DMODEL;               // 6 MB
  bf16* Qw = Wb + (size_t)3*DMODEL*DMODEL;            // 8 MB
  bf16* Kw = Qw + (size_t)NROWS*DMODEL;               // 8 MB
  bf16* Vw = Kw + (size_t)NROWS*DMODEL;               // 8 MB
  unsigned long long* Mb = (unsigned long long*)(Vw + (size_t)NROWS*DMODEL);  // 512 B

  cvt_all<<<3585, 256, 0, stream>>>(hs, Wq, Wk, Wv, mask, Xb, Wb, Mb);

  qkv_gemm<<<dim3(NROWS/BM, 3*DMODEL/BN), 256, 0, stream>>>(Xb, Wb, bq, bk, bv, Qw, Kw, Vw);

  attn_mfma<<<dim3(BATCH*NHEAD, S_LEN/QBLK), 256, 0, stream>>>(Qw, Kw, Vw, Mb, out);
}

// Round 13
// 78.163 us; speedup vs baseline: 1.1287x; 1.0618x over previous
//
#include <hip/hip_runtime.h>
#include <hip/hip_bf16.h>

#define S_LEN  1024
#define BATCH  4
#define DMODEL 1024
#define NHEAD  16
#define DHEAD  64
#define NROWS  (S_LEN*BATCH)   // 4096

typedef __bf16 bf16;
typedef __bf16 bf16x2 __attribute__((ext_vector_type(2)));
typedef __bf16 bf16x4 __attribute__((ext_vector_type(4)));
typedef __bf16 bf16x8 __attribute__((ext_vector_type(8)));
typedef float  f32x4  __attribute__((ext_vector_type(4)));
typedef float  f32x16 __attribute__((ext_vector_type(16)));

#define AS1 __attribute__((address_space(1)))
#define AS3 __attribute__((address_space(3)))

#define QSCALE  0.18033688011112042f   // 0.125 * log2(e)

__device__ __forceinline__ void gload16(const bf16* g, bf16* l) {
  __builtin_amdgcn_global_load_lds((const AS1 void*)g, (AS3 void*)l, 16, 0, 0);
}

__device__ __forceinline__ float fast_exp2(float x) {
#if __has_builtin(__builtin_amdgcn_exp2f)
  return __builtin_amdgcn_exp2f(x);
#else
  return exp2f(x);
#endif
}

// ---------------- fused fp32 -> bf16 convert + mask bitmask ----------------
__global__ __launch_bounds__(256) void cvt_all(
    const float* __restrict__ hs, const float* __restrict__ wq,
    const float* __restrict__ wk, const float* __restrict__ wv,
    const float* __restrict__ mask,
    bf16* __restrict__ Xb, bf16* __restrict__ Wb,
    unsigned long long* __restrict__ mbits)
{
  const int b = blockIdx.x;
  if (b == 3584) {   // mask -> per-tile 64-bit masked-position bitmask
    const int wv = threadIdx.x >> 6, lane = threadIdx.x & 63;
    #pragma unroll
    for (int t16 = 0; t16 < 16; ++t16) {
      const float v = mask[(size_t)wv*S_LEN + t16*64 + lane];
      const unsigned long long bal = __ballot(v < -1000.f);
      if (lane == 0) mbits[wv*16 + t16] = bal;
    }
    return;
  }
  const float* src; bf16* dst; int i;
  if (b < 2048)      { src = hs; dst = Xb;                           i = b*256        + threadIdx.x; }
  else if (b < 2560) { src = wq; dst = Wb;                           i = (b-2048)*256 + threadIdx.x; }
  else if (b < 3072) { src = wk; dst = Wb + (size_t)DMODEL*DMODEL;   i = (b-2560)*256 + threadIdx.x; }
  else               { src = wv; dst = Wb + (size_t)2*DMODEL*DMODEL; i = (b-3072)*256 + threadIdx.x; }
  const float4* s4 = (const float4*)src;
  float4 a = s4[2*i], c = s4[2*i+1];
  bf16x8 o;
  o[0]=(bf16)a.x; o[1]=(bf16)a.y; o[2]=(bf16)a.z; o[3]=(bf16)a.w;
  o[4]=(bf16)c.x; o[5]=(bf16)c.y; o[6]=(bf16)c.z; o[7]=(bf16)c.w;
  ((bf16x8*)dst)[i] = o;
}

// ---------------- fused QKV GEMM: exact r3 m97 structure (measured ~27us) ----------------
#define BM 128
#define BN 128
#define BK 32

__global__ __launch_bounds__(256) void qkv_gemm(
    const bf16* __restrict__ X, const bf16* __restrict__ Wcat,
    const float* __restrict__ bq, const float* __restrict__ bk, const float* __restrict__ bv,
    bf16* __restrict__ Qo, bf16* __restrict__ Ko, bf16* __restrict__ Vo)
{
  __shared__ __align__(16) bf16 As[BM*BK];   // 8 KB linear
  __shared__ __align__(16) bf16 Bs[BN*BK];   // 8 KB

  const int tid  = threadIdx.x;
  const int row0 = blockIdx.x * BM;
  const int col0 = blockIdx.y * BN;
  const int wsel = col0 >> 10;
  const int coln = col0 & 1023;

  const int wv   = tid >> 6;
  const int lane = tid & 63;
  const int lg   = lane >> 4;
  const int lr   = lane & 15;
  const int wr   = (wv >> 1) << 6;
  const int wc   = (wv & 1) << 6;

  const int c0 = tid, c1 = tid + 256;
  const size_t gA0 = (size_t)(row0 + (c0>>2))*DMODEL + (size_t)((c0&3)<<3);
  const size_t gA1 = (size_t)(row0 + (c1>>2))*DMODEL + (size_t)((c1&3)<<3);
  const size_t gB0 = (size_t)(col0 + (c0>>2))*DMODEL + (size_t)((c0&3)<<3);
  const size_t gB1 = (size_t)(col0 + (c1>>2))*DMODEL + (size_t)((c1&3)<<3);
  const int wb = (tid >> 6) << 6;
  bf16* lA0 = As + (size_t)wb*8;
  bf16* lA1 = As + (size_t)(wb+256)*8;
  bf16* lB0 = Bs + (size_t)wb*8;
  bf16* lB1 = Bs + (size_t)(wb+256)*8;

  f32x4 acc[4][4];
  #pragma unroll
  for (int mi=0; mi<4; ++mi)
    #pragma unroll
    for (int ni=0; ni<4; ++ni)
      acc[mi][ni] = (f32x4){0.f,0.f,0.f,0.f};

  for (int k0 = 0; k0 < DMODEL; k0 += BK) {
    __syncthreads();
    gload16(X    + gA0 + k0, lA0);
    gload16(X    + gA1 + k0, lA1);
    gload16(Wcat + gB0 + k0, lB0);
    gload16(Wcat + gB1 + k0, lB1);
    __syncthreads();

    bf16x8 af[4], bfr[4];
    #pragma unroll
    for (int mi=0; mi<4; ++mi)
      af[mi] = *(const bf16x8*)&As[(wr + mi*16 + lr)*BK + lg*8];
    #pragma unroll
    for (int ni=0; ni<4; ++ni)
      bfr[ni] = *(const bf16x8*)&Bs[(wc + ni*16 + lr)*BK + lg*8];

    #pragma unroll
    for (int mi=0; mi<4; ++mi)
      #pragma unroll
      for (int ni=0; ni<4; ++ni)
        acc[mi][ni] = __builtin_amdgcn_mfma_f32_16x16x32_bf16(af[mi], bfr[ni], acc[mi][ni], 0, 0, 0);
  }

  const float* bias = (wsel==0) ? bq : ((wsel==1) ? bk : bv);
  bf16* Out = (wsel==0) ? Qo : ((wsel==1) ? Ko : Vo);
  const float oscale = (wsel==0) ? QSCALE : 1.0f;

  #pragma unroll
  for (int ni=0; ni<4; ++ni) {
    const int co = coln + wc + ni*16 + lr;
    const float bias_v = bias[co];
    const int h  = co >> 6;
    const int dh = co & 63;
    #pragma unroll
    for (int mi=0; mi<4; ++mi) {
      #pragma unroll
      for (int p=0; p<4; ++p) {
        const int gr = row0 + wr + mi*16 + lg*4 + p;
        const int s_ = gr >> 2;
        const int b_ = gr & 3;
        Out[((size_t)(b_*NHEAD + h)*S_LEN + s_)*DHEAD + dh] = (bf16)((acc[mi][ni][p] + bias_v) * oscale);
      }
    }
  }
}

// ---------------- MFMA flash attention: r12 body, QBLK=256, 8 waves, 1 block/CU ----------------
// One block serves 256 q-rows of one head -> K/V staged ONCE per CU (was twice).
// 32x32 MFMA, swapped QK^T, zero-shuffle P, bitmask mask, XOR chunk-swizzle, dbuf.
#define QBLK 256
#define LSW(row, chunk) (((row)<<6) + ((((chunk) ^ ((row)&7)))<<3))

__global__ __launch_bounds__(512, 2) void attn_mfma(
    const bf16* __restrict__ Q, const bf16* __restrict__ K, const bf16* __restrict__ V,
    const unsigned long long* __restrict__ mbits, float* __restrict__ out)
{
  __shared__ __align__(16) bf16 Ks[2][64*64];   // 16 KB
  __shared__ __align__(16) bf16 Vt[2][64*64];   // 16 KB (V^T, swizzled)
  __shared__ float Linv[8][32];                 // 1 KB

  const int bh   = blockIdx.x;
  const int b_   = bh >> 4;
  const int h_   = bh & 15;
  const int tid  = threadIdx.x;
  const int wv   = tid >> 6;             // 0..7
  const int lane = tid & 63;
  const int l31  = lane & 31;
  const int hh   = lane >> 5;            // 0/1
  const int q0   = blockIdx.y * QBLK;

  // ---- Q B-frags from global (pre-scaled by QSCALE in gemm): q = lane&31 ----
  const bf16* Qp = Q + ((size_t)bh*S_LEN + q0 + wv*32 + l31)*DHEAD;
  bf16x8 qb[4];
  #pragma unroll
  for (int dk=0; dk<4; ++dk) qb[dk] = *(const bf16x8*)&Qp[dk*16 + hh*8];

  const bf16* Kb = K + (size_t)bh*S_LEN*DHEAD;
  const bf16* Vb = V + (size_t)bh*S_LEN*DHEAD;
  const unsigned long long* mbp = mbits + (size_t)b_*16;

  // staging maps (512 threads; half the per-thread work of the 256-thread version)
  const int krow = tid >> 3, kch = tid & 7;   // K: one granule (row, chunk)
  const int vrow = tid & 63, vcb = tid >> 6;  // V: row=lane, 8 d-cols starting vcb*8

  // ---- prologue: stage tile 0 ----
  bf16x8 kr0 = *(const bf16x8*)&Kb[(size_t)krow*DHEAD + kch*8];
  bf16x8 vr0 = *(const bf16x8*)&Vb[(size_t)vrow*DHEAD + vcb*8];
  {
    *(bf16x8*)&Ks[0][LSW(krow, kch)] = kr0;
    #pragma unroll
    for (int i=0;i<8;++i) {
      const int d0 = vcb*8 + i;
      Vt[0][(d0<<6) + (((vrow>>3) ^ (d0&7))<<3) + (vrow&7)] = vr0[i];
    }
  }
  __syncthreads();

  f32x16 ctx[2];
  ctx[0] = (f32x16)0.f; ctx[1] = (f32x16)0.f;
  float lsum = 0.f;

  for (int t = 0; t < 16; ++t) {
    const bf16* Kc = Ks[t & 1];
    const bf16* Vc = Vt[t & 1];

    // issue next tile's global loads early
    if (t < 15) {
      const size_t nb = (size_t)(t+1)*64;
      kr0 = *(const bf16x8*)&Kb[(nb+krow)*DHEAD + kch*8];
      vr0 = *(const bf16x8*)&Vb[(nb+vrow)*DHEAD + vcb*8];
    }

    // ---- QK^T (swapped): D[t][q], 2 t-tiles of 32, contraction dh=64 ----
    f32x16 sacc[2];
    sacc[0] = (f32x16)0.f; sacc[1] = (f32x16)0.f;
    __builtin_amdgcn_s_setprio(1);
    #pragma unroll
    for (int tt=0; tt<2; ++tt) {
      const int row = tt*32 + l31;
      #pragma unroll
      for (int dk=0; dk<4; ++dk) {
        bf16x8 ka = *(const bf16x8*)&Kc[LSW(row, dk*2 + hh)];
        sacc[tt] = __builtin_amdgcn_mfma_f32_32x32x16_bf16(ka, qb[dk], sacc[tt], 0,0,0);
      }
    }
    __builtin_amdgcn_s_setprio(0);

    // ---- softmax: p = bit ? 0 : exp2(s); pack to PV A-frags in-lane ----
    const unsigned long long mt = mbp[t];
    bf16x8 pf[2][2];
    #pragma unroll
    for (int tt=0; tt<2; ++tt) {
      const unsigned int mw = (unsigned int)(mt >> (tt*32 + 4*hh));
      float pe[16];
      #pragma unroll
      for (int e=0; e<16; ++e) {
        const float ex = fast_exp2(sacc[tt][e]);
        pe[e] = ((mw >> ((e&3) + 8*(e>>2))) & 1u) ? 0.f : ex;
        lsum += pe[e];
      }
      union { bf16x2 h2[8]; bf16x8 v[2]; } u;
      #pragma unroll
      for (int j=0; j<8; ++j) { bf16x2 p2; p2[0]=(bf16)pe[2*j]; p2[1]=(bf16)pe[2*j+1]; u.h2[j]=p2; }
      pf[tt][0] = u.v[0]; pf[tt][1] = u.v[1];
    }

    // ---- PV: O[q][d] += P * V ; B-frags via slot->t map (2x b64 each) ----
    __builtin_amdgcn_s_setprio(1);
    #pragma unroll
    for (int nt=0; nt<2; ++nt) {
      const int drow = nt*32 + l31;
      const int dbase = (drow<<6) + 4*hh;
      const int dsw = (drow&7);
      #pragma unroll
      for (int tt=0; tt<2; ++tt) {
        #pragma unroll
        for (int kk=0; kk<2; ++kk) {
          const int lc = tt*4 + kk*2;
          bf16x4 lo = *(const bf16x4*)&Vc[dbase + (((lc  ) ^ dsw)<<3)];
          bf16x4 hi = *(const bf16x4*)&Vc[dbase + (((lc+1) ^ dsw)<<3)];
          bf16x8 vb;
          #pragma unroll
          for (int j=0; j<4; ++j) { vb[j]=lo[j]; vb[4+j]=hi[j]; }
          ctx[nt] = __builtin_amdgcn_mfma_f32_32x32x16_bf16(pf[tt][kk], vb, ctx[nt], 0,0,0);
        }
      }
    }
    __builtin_amdgcn_s_setprio(0);

    // ---- stage next tile into other buffer ----
    if (t < 15) {
      bf16* Kn = (bf16*)Ks[(t+1) & 1];
      bf16* Vn = (bf16*)Vt[(t+1) & 1];
      *(bf16x8*)&Kn[LSW(krow, kch)] = kr0;
      #pragma unroll
      for (int i=0;i<8;++i) {
        const int d0 = vcb*8 + i;
        Vn[(d0<<6) + (((vrow>>3) ^ (d0&7))<<3) + (vrow&7)] = vr0[i];
      }
    }
    __syncthreads();
  }

  // ---- lsum: partner-half add, distribute 1/lsum via per-wave LDS row ----
  const float tot = lsum + __shfl_xor(lsum, 32);
  if (lane < 32) Linv[wv][l31] = 1.f / tot;
  f32x4 inv4[4];
  #pragma unroll
  for (int g4=0; g4<4; ++g4) inv4[g4] = *(const f32x4*)&Linv[wv][8*g4 + 4*hh];

  // ---- write out: out[qg][b][h*64 + nt*32 + (lane&31)] ----
  float* op = out + ((size_t)(q0 + wv*32)*BATCH + b_)*DMODEL + h_*DHEAD + l31;
  #pragma unroll
  for (int e=0; e<16; ++e) {
    const int qe = (e&3) + 8*(e>>2) + 4*hh;
    const float inv = inv4[e>>2][e&3];
    float* oq = op + (size_t)qe*BATCH*DMODEL;
    oq[0]  = ctx[0][e] * inv;
    oq[32] = ctx[1][e] * inv;
  }
}

// ---------------- launch ----------------
extern "C" void kernel_launch(void* const* d_in, const int* in_sizes, int n_in,
                              void* d_out, int out_size, void* d_ws, size_t ws_size,
                              hipStream_t stream) {
  const float* hs   = (const float*)d_in[0];
  const float* mask = (const float*)d_in[1];
  const float* Wq   = (const float*)d_in[2];
  const float* bq   = (const float*)d_in[3];
  const float* Wk   = (const float*)d_in[4];
  const float* bk   = (const float*)d_in[5];
  const float* Wv   = (const float*)d_in[6];
  const float* bv   = (const float*)d_in[7];
  float* out = (float*)d_out;

  char* ws = (char*)d_ws;
  bf16* Xb = (bf16*)ws;                               // 8 MB
  bf16* Wb = Xb + (size_t)NROWS*DMODEL;               // 6 MB
  bf16* Qw = Wb + (size_t)3*DMODEL*DMODEL;            // 8 MB
  bf16* Kw = Qw + (size_t)NROWS*DMODEL;               // 8 MB
  bf16* Vw = Kw + (size_t)NROWS*DMODEL;               // 8 MB
  unsigned long long* Mb = (unsigned long long*)(Vw + (size_t)NROWS*DMODEL);  // 512 B

  cvt_all<<<3585, 256, 0, stream>>>(hs, Wq, Wk, Wv, mask, Xb, Wb, Mb);

  qkv_gemm<<<dim3(NROWS/BM, 3*DMODEL/BN), 256, 0, stream>>>(Xb, Wb, bq, bk, bv, Qw, Kw, Vw);

  attn_mfma<<<dim3(BATCH*NHEAD, S_LEN/QBLK), 512, 0, stream>>>(Qw, Kw, Vw, Mb, out);
}

// Round 14
// 78.117 us; speedup vs baseline: 1.1293x; 1.0006x over previous
//
#include <hip/hip_runtime.h>
#include <hip/hip_bf16.h>

#define S_LEN  1024
#define BATCH  4
#define DMODEL 1024
#define NHEAD  16
#define DHEAD  64
#define NROWS  (S_LEN*BATCH)   // 4096

typedef __bf16 bf16;
typedef __bf16 bf16x2 __attribute__((ext_vector_type(2)));
typedef __bf16 bf16x4 __attribute__((ext_vector_type(4)));
typedef __bf16 bf16x8 __attribute__((ext_vector_type(8)));
typedef float  f32x4  __attribute__((ext_vector_type(4)));
typedef float  f32x16 __attribute__((ext_vector_type(16)));

#define AS1 __attribute__((address_space(1)))
#define AS3 __attribute__((address_space(3)))

#define QSCALE  0.18033688011112042f   // 0.125 * log2(e)

__device__ __forceinline__ void gload16(const bf16* g, bf16* l) {
  __builtin_amdgcn_global_load_lds((const AS1 void*)g, (AS3 void*)l, 16, 0, 0);
}

__device__ __forceinline__ float fast_exp2(float x) {
#if __has_builtin(__builtin_amdgcn_exp2f)
  return __builtin_amdgcn_exp2f(x);
#else
  return exp2f(x);
#endif
}

// ---------------- fused fp32 -> bf16 convert + mask bitmask ----------------
__global__ __launch_bounds__(256) void cvt_all(
    const float* __restrict__ hs, const float* __restrict__ wq,
    const float* __restrict__ wk, const float* __restrict__ wv,
    const float* __restrict__ mask,
    bf16* __restrict__ Xb, bf16* __restrict__ Wb,
    unsigned long long* __restrict__ mbits)
{
  const int b = blockIdx.x;
  if (b == 3584) {   // mask -> per-tile 64-bit masked-position bitmask
    const int wv = threadIdx.x >> 6, lane = threadIdx.x & 63;
    #pragma unroll
    for (int t16 = 0; t16 < 16; ++t16) {
      const float v = mask[(size_t)wv*S_LEN + t16*64 + lane];
      const unsigned long long bal = __ballot(v < -1000.f);
      if (lane == 0) mbits[wv*16 + t16] = bal;
    }
    return;
  }
  const float* src; bf16* dst; int i;
  if (b < 2048)      { src = hs; dst = Xb;                           i = b*256        + threadIdx.x; }
  else if (b < 2560) { src = wq; dst = Wb;                           i = (b-2048)*256 + threadIdx.x; }
  else if (b < 3072) { src = wk; dst = Wb + (size_t)DMODEL*DMODEL;   i = (b-2560)*256 + threadIdx.x; }
  else               { src = wv; dst = Wb + (size_t)2*DMODEL*DMODEL; i = (b-3072)*256 + threadIdx.x; }
  const float4* s4 = (const float4*)src;
  float4 a = s4[2*i], c = s4[2*i+1];
  bf16x8 o;
  o[0]=(bf16)a.x; o[1]=(bf16)a.y; o[2]=(bf16)a.z; o[3]=(bf16)a.w;
  o[4]=(bf16)c.x; o[5]=(bf16)c.y; o[6]=(bf16)c.z; o[7]=(bf16)c.w;
  ((bf16x8*)dst)[i] = o;
}

// ---------------- fused QKV GEMM: exact r3 m97 structure (measured ~27us) ----------------
#define BM 128
#define BN 128
#define BK 32

__global__ __launch_bounds__(256) void qkv_gemm(
    const bf16* __restrict__ X, const bf16* __restrict__ Wcat,
    const float* __restrict__ bq, const float* __restrict__ bk, const float* __restrict__ bv,
    bf16* __restrict__ Qo, bf16* __restrict__ Ko, bf16* __restrict__ Vo)
{
  __shared__ __align__(16) bf16 As[BM*BK];   // 8 KB linear
  __shared__ __align__(16) bf16 Bs[BN*BK];   // 8 KB

  const int tid  = threadIdx.x;
  const int row0 = blockIdx.x * BM;
  const int col0 = blockIdx.y * BN;
  const int wsel = col0 >> 10;
  const int coln = col0 & 1023;

  const int wv   = tid >> 6;
  const int lane = tid & 63;
  const int lg   = lane >> 4;
  const int lr   = lane & 15;
  const int wr   = (wv >> 1) << 6;
  const int wc   = (wv & 1) << 6;

  const int c0 = tid, c1 = tid + 256;
  const size_t gA0 = (size_t)(row0 + (c0>>2))*DMODEL + (size_t)((c0&3)<<3);
  const size_t gA1 = (size_t)(row0 + (c1>>2))*DMODEL + (size_t)((c1&3)<<3);
  const size_t gB0 = (size_t)(col0 + (c0>>2))*DMODEL + (size_t)((c0&3)<<3);
  const size_t gB1 = (size_t)(col0 + (c1>>2))*DMODEL + (size_t)((c1&3)<<3);
  const int wb = (tid >> 6) << 6;
  bf16* lA0 = As + (size_t)wb*8;
  bf16* lA1 = As + (size_t)(wb+256)*8;
  bf16* lB0 = Bs + (size_t)wb*8;
  bf16* lB1 = Bs + (size_t)(wb+256)*8;

  f32x4 acc[4][4];
  #pragma unroll
  for (int mi=0; mi<4; ++mi)
    #pragma unroll
    for (int ni=0; ni<4; ++ni)
      acc[mi][ni] = (f32x4){0.f,0.f,0.f,0.f};

  for (int k0 = 0; k0 < DMODEL; k0 += BK) {
    __syncthreads();
    gload16(X    + gA0 + k0, lA0);
    gload16(X    + gA1 + k0, lA1);
    gload16(Wcat + gB0 + k0, lB0);
    gload16(Wcat + gB1 + k0, lB1);
    __syncthreads();

    bf16x8 af[4], bfr[4];
    #pragma unroll
    for (int mi=0; mi<4; ++mi)
      af[mi] = *(const bf16x8*)&As[(wr + mi*16 + lr)*BK + lg*8];
    #pragma unroll
    for (int ni=0; ni<4; ++ni)
      bfr[ni] = *(const bf16x8*)&Bs[(wc + ni*16 + lr)*BK + lg*8];

    #pragma unroll
    for (int mi=0; mi<4; ++mi)
      #pragma unroll
      for (int ni=0; ni<4; ++ni)
        acc[mi][ni] = __builtin_amdgcn_mfma_f32_16x16x32_bf16(af[mi], bfr[ni], acc[mi][ni], 0, 0, 0);
  }

  const float* bias = (wsel==0) ? bq : ((wsel==1) ? bk : bv);
  bf16* Out = (wsel==0) ? Qo : ((wsel==1) ? Ko : Vo);
  const float oscale = (wsel==0) ? QSCALE : 1.0f;

  #pragma unroll
  for (int ni=0; ni<4; ++ni) {
    const int co = coln + wc + ni*16 + lr;
    const float bias_v = bias[co];
    const int h  = co >> 6;
    const int dh = co & 63;
    #pragma unroll
    for (int mi=0; mi<4; ++mi) {
      #pragma unroll
      for (int p=0; p<4; ++p) {
        const int gr = row0 + wr + mi*16 + lg*4 + p;
        const int s_ = gr >> 2;
        const int b_ = gr & 3;
        Out[((size_t)(b_*NHEAD + h)*S_LEN + s_)*DHEAD + dh] = (bf16)((acc[mi][ni][p] + bias_v) * oscale);
      }
    }
  }
}

// ---------------- MFMA flash attention: r12 body verbatim (measured ~31-32us) ----------------
// 4 waves x 32 q, QBLK=128, KVB=64, dbuf K/V, XOR chunk-swizzle, zero-shuffle P,
// swapped QK^T (D[t][q], q=lane&31), mask as 64-bit bitmask (p = bit ? 0 : exp2(s)).
#define QBLK 128
#define LSW(row, chunk) (((row)<<6) + ((((chunk) ^ ((row)&7)))<<3))

__global__ __launch_bounds__(256, 2) void attn_mfma(
    const bf16* __restrict__ Q, const bf16* __restrict__ K, const bf16* __restrict__ V,
    const unsigned long long* __restrict__ mbits, float* __restrict__ out)
{
  __shared__ __align__(16) bf16 Ks[2][64*64];   // 16 KB
  __shared__ __align__(16) bf16 Vt[2][64*64];   // 16 KB (V^T, swizzled)
  __shared__ float Linv[4][32];                 // 512 B

  const int bh   = blockIdx.x;
  const int b_   = bh >> 4;
  const int h_   = bh & 15;
  const int tid  = threadIdx.x;
  const int wv   = tid >> 6;             // 0..3
  const int lane = tid & 63;
  const int l31  = lane & 31;
  const int hh   = lane >> 5;            // 0/1
  const int q0   = blockIdx.y * QBLK;

  // ---- Q B-frags from global (pre-scaled by QSCALE in gemm): q = lane&31 ----
  const bf16* Qp = Q + ((size_t)bh*S_LEN + q0 + wv*32 + l31)*DHEAD;
  bf16x8 qb[4];
  #pragma unroll
  for (int dk=0; dk<4; ++dk) qb[dk] = *(const bf16x8*)&Qp[dk*16 + hh*8];

  const bf16* Kb = K + (size_t)bh*S_LEN*DHEAD;
  const bf16* Vb = V + (size_t)bh*S_LEN*DHEAD;
  const unsigned long long* mbp = mbits + (size_t)b_*16;

  // staging maps (256 threads)
  const int krow = tid >> 2, kch = tid & 3;   // K: row, chunks kch & kch+4
  const int vrow = tid & 63, vcb = tid >> 6;  // V: row=lane, 16 cols starting vcb*16

  // ---- prologue: stage tile 0 ----
  bf16x8 kr0 = *(const bf16x8*)&Kb[(size_t)krow*DHEAD + kch*8];
  bf16x8 kr1 = *(const bf16x8*)&Kb[(size_t)krow*DHEAD + kch*8 + 32];
  bf16x8 vr0 = *(const bf16x8*)&Vb[(size_t)vrow*DHEAD + vcb*16];
  bf16x8 vr1 = *(const bf16x8*)&Vb[(size_t)vrow*DHEAD + vcb*16 + 8];
  {
    *(bf16x8*)&Ks[0][LSW(krow, kch)]   = kr0;
    *(bf16x8*)&Ks[0][LSW(krow, kch+4)] = kr1;
    #pragma unroll
    for (int i=0;i<8;++i) {
      const int d0 = vcb*16 + i, d1 = d0 + 8;
      Vt[0][(d0<<6) + (((vrow>>3) ^ (d0&7))<<3) + (vrow&7)] = vr0[i];
      Vt[0][(d1<<6) + (((vrow>>3) ^ (d1&7))<<3) + (vrow&7)] = vr1[i];
    }
  }
  __syncthreads();

  f32x16 ctx[2];
  ctx[0] = (f32x16)0.f; ctx[1] = (f32x16)0.f;
  float lsum = 0.f;

  for (int t = 0; t < 16; ++t) {
    const bf16* Kc = Ks[t & 1];
    const bf16* Vc = Vt[t & 1];

    // issue next tile's global loads early
    if (t < 15) {
      const size_t nb = (size_t)(t+1)*64;
      kr0 = *(const bf16x8*)&Kb[(nb+krow)*DHEAD + kch*8];
      kr1 = *(const bf16x8*)&Kb[(nb+krow)*DHEAD + kch*8 + 32];
      vr0 = *(const bf16x8*)&Vb[(nb+vrow)*DHEAD + vcb*16];
      vr1 = *(const bf16x8*)&Vb[(nb+vrow)*DHEAD + vcb*16 + 8];
    }

    // ---- QK^T (swapped): D[t][q], 2 t-tiles of 32, contraction dh=64 ----
    f32x16 sacc[2];
    sacc[0] = (f32x16)0.f; sacc[1] = (f32x16)0.f;
    __builtin_amdgcn_s_setprio(1);
    #pragma unroll
    for (int tt=0; tt<2; ++tt) {
      const int row = tt*32 + l31;
      #pragma unroll
      for (int dk=0; dk<4; ++dk) {
        bf16x8 ka = *(const bf16x8*)&Kc[LSW(row, dk*2 + hh)];
        sacc[tt] = __builtin_amdgcn_mfma_f32_32x32x16_bf16(ka, qb[dk], sacc[tt], 0,0,0);
      }
    }
    __builtin_amdgcn_s_setprio(0);

    // ---- softmax: p = bit ? 0 : exp2(s); pack to PV A-frags in-lane ----
    const unsigned long long mt = mbp[t];
    bf16x8 pf[2][2];
    #pragma unroll
    for (int tt=0; tt<2; ++tt) {
      const unsigned int mw = (unsigned int)(mt >> (tt*32 + 4*hh));
      float pe[16];
      #pragma unroll
      for (int e=0; e<16; ++e) {
        const float ex = fast_exp2(sacc[tt][e]);
        pe[e] = ((mw >> ((e&3) + 8*(e>>2))) & 1u) ? 0.f : ex;
        lsum += pe[e];
      }
      union { bf16x2 h2[8]; bf16x8 v[2]; } u;
      #pragma unroll
      for (int j=0; j<8; ++j) { bf16x2 p2; p2[0]=(bf16)pe[2*j]; p2[1]=(bf16)pe[2*j+1]; u.h2[j]=p2; }
      pf[tt][0] = u.v[0]; pf[tt][1] = u.v[1];
    }

    // ---- PV: O[q][d] += P * V ; B-frags via slot->t map (2x b64 each) ----
    __builtin_amdgcn_s_setprio(1);
    #pragma unroll
    for (int nt=0; nt<2; ++nt) {
      const int drow = nt*32 + l31;
      const int dbase = (drow<<6) + 4*hh;
      const int dsw = (drow&7);
      #pragma unroll
      for (int tt=0; tt<2; ++tt) {
        #pragma unroll
        for (int kk=0; kk<2; ++kk) {
          const int lc = tt*4 + kk*2;
          bf16x4 lo = *(const bf16x4*)&Vc[dbase + (((lc  ) ^ dsw)<<3)];
          bf16x4 hi = *(const bf16x4*)&Vc[dbase + (((lc+1) ^ dsw)<<3)];
          bf16x8 vb;
          #pragma unroll
          for (int j=0; j<4; ++j) { vb[j]=lo[j]; vb[4+j]=hi[j]; }
          ctx[nt] = __builtin_amdgcn_mfma_f32_32x32x16_bf16(pf[tt][kk], vb, ctx[nt], 0,0,0);
        }
      }
    }
    __builtin_amdgcn_s_setprio(0);

    // ---- stage next tile into other buffer ----
    if (t < 15) {
      bf16* Kn = (bf16*)Ks[(t+1) & 1];
      bf16* Vn = (bf16*)Vt[(t+1) & 1];
      *(bf16x8*)&Kn[LSW(krow, kch)]   = kr0;
      *(bf16x8*)&Kn[LSW(krow, kch+4)] = kr1;
      #pragma unroll
      for (int i=0;i<8;++i) {
        const int d0 = vcb*16 + i, d1 = d0 + 8;
        Vn[(d0<<6) + (((vrow>>3) ^ (d0&7))<<3) + (vrow&7)] = vr0[i];
        Vn[(d1<<6) + (((vrow>>3) ^ (d1&7))<<3) + (vrow&7)] = vr1[i];
      }
    }
    __syncthreads();
  }

  // ---- lsum: partner-half add, distribute 1/lsum via per-wave LDS row ----
  const float tot = lsum + __shfl_xor(lsum, 32);
  if (lane < 32) Linv[wv][l31] = 1.f / tot;
  f32x4 inv4[4];
  #pragma unroll
  for (int g4=0; g4<4; ++g4) inv4[g4] = *(const f32x4*)&Linv[wv][8*g4 + 4*hh];

  // ---- write out: out[qg][b][h*64 + nt*32 + (lane&31)] ----
  float* op = out + ((size_t)(q0 + wv*32)*BATCH + b_)*DMODEL + h_*DHEAD + l31;
  #pragma unroll
  for (int e=0; e<16; ++e) {
    const int qe = (e&3) + 8*(e>>2) + 4*hh;
    const float inv = inv4[e>>2][e&3];
    float* oq = op + (size_t)qe*BATCH*DMODEL;
    oq[0]  = ctx[0][e] * inv;
    oq[32] = ctx[1][e] * inv;
  }
}

// ---------------- launch ----------------
extern "C" void kernel_launch(void* const* d_in, const int* in_sizes, int n_in,
                              void* d_out, int out_size, void* d_ws, size_t ws_size,
                              hipStream_t stream) {
  const float* hs   = (const float*)d_in[0];
  const float* mask = (const float*)d_in[1];
  const float* Wq   = (const float*)d_in[2];
  const float* bq   = (const float*)d_in[3];
  const float* Wk   = (const float*)d_in[4];
  const float* bk   = (const float*)d_in[5];
  const float* Wv   = (const float*)d_in[6];
  const float* bv   = (const float*)d_in[7];
  float* out = (float*)d_out;

  char* ws = (char*)d_ws;
  bf16* Xb = (bf16*)ws;                               // 8 MB
  bf16* Wb = Xb + (size_t)NROWS*DMODEL;               // 6 MB
  bf16* Qw = Wb + (size_t)3*DMODEL*DMODEL;            // 8 MB
  bf16* Kw = Qw + (size_t)NROWS*DMODEL;               // 8 MB
  bf16* Vw = Kw + (size_t)NROWS*DMODEL;               // 8 MB
  unsigned long long* Mb = (unsigned long long*)(Vw + (size_t)NROWS*DMODEL);  // 512 B

  cvt_all<<<3585, 256, 0, stream>>>(hs, Wq, Wk, Wv, mask, Xb, Wb, Mb);

  qkv_gemm<<<dim3(NROWS/BM, 3*DMODEL/BN), 256, 0, stream>>>(Xb, Wb, bq, bk, bv, Qw, Kw, Vw);

  attn_mfma<<<dim3(BATCH*NHEAD, S_LEN/QBLK), 256, 0, stream>>>(Qw, Kw, Vw, Mb, out);
}

// Round 15
// 71.248 us; speedup vs baseline: 1.2382x; 1.0964x over previous
//
#include <hip/hip_runtime.h>
#include <hip/hip_bf16.h>

#define S_LEN  1024
#define BATCH  4
#define DMODEL 1024
#define NHEAD  16
#define DHEAD  64
#define NROWS  (S_LEN*BATCH)   // 4096

typedef __bf16 bf16;
typedef __bf16 bf16x2 __attribute__((ext_vector_type(2)));
typedef __bf16 bf16x4 __attribute__((ext_vector_type(4)));
typedef __bf16 bf16x8 __attribute__((ext_vector_type(8)));
typedef float  f32x4  __attribute__((ext_vector_type(4)));
typedef float  f32x16 __attribute__((ext_vector_type(16)));

#define AS1 __attribute__((address_space(1)))
#define AS3 __attribute__((address_space(3)))

#define QSCALE  0.18033688011112042f   // 0.125 * log2(e)

__device__ __forceinline__ void gload16(const bf16* g, bf16* l) {
  __builtin_amdgcn_global_load_lds((const AS1 void*)g, (AS3 void*)l, 16, 0, 0);
}

__device__ __forceinline__ float fast_exp2(float x) {
#if __has_builtin(__builtin_amdgcn_exp2f)
  return __builtin_amdgcn_exp2f(x);
#else
  return exp2f(x);
#endif
}

// ---------------- fused fp32 -> bf16 convert ----------------
__global__ __launch_bounds__(256) void cvt_all(
    const float* __restrict__ hs, const float* __restrict__ wq,
    const float* __restrict__ wk, const float* __restrict__ wv,
    bf16* __restrict__ Xb, bf16* __restrict__ Wb)
{
  const int b = blockIdx.x;
  const float* src; bf16* dst; int i;
  if (b < 2048)      { src = hs; dst = Xb;                           i = b*256        + threadIdx.x; }
  else if (b < 2560) { src = wq; dst = Wb;                           i = (b-2048)*256 + threadIdx.x; }
  else if (b < 3072) { src = wk; dst = Wb + (size_t)DMODEL*DMODEL;   i = (b-2560)*256 + threadIdx.x; }
  else               { src = wv; dst = Wb + (size_t)2*DMODEL*DMODEL; i = (b-3072)*256 + threadIdx.x; }
  const float4* s4 = (const float4*)src;
  float4 a = s4[2*i], c = s4[2*i+1];
  bf16x8 o;
  o[0]=(bf16)a.x; o[1]=(bf16)a.y; o[2]=(bf16)a.z; o[3]=(bf16)a.w;
  o[4]=(bf16)c.x; o[5]=(bf16)c.y; o[6]=(bf16)c.z; o[7]=(bf16)c.w;
  ((bf16x8*)dst)[i] = o;
}

// ---------------- fused QKV GEMM, m97 structure (measured ~27-28us) ----------------
#define BM 128
#define BN 128
#define BK 32

__global__ __launch_bounds__(256) void qkv_gemm(
    const bf16* __restrict__ X, const bf16* __restrict__ Wcat,
    const float* __restrict__ bq, const float* __restrict__ bk, const float* __restrict__ bv,
    bf16* __restrict__ Qo, bf16* __restrict__ Ko, bf16* __restrict__ Vo)
{
  __shared__ __align__(16) bf16 As[BM*BK];   // 8 KB linear
  __shared__ __align__(16) bf16 Bs[BN*BK];   // 8 KB

  const int tid  = threadIdx.x;
  const int row0 = blockIdx.x * BM;
  const int col0 = blockIdx.y * BN;
  const int wsel = col0 >> 10;
  const int coln = col0 & 1023;

  const int wv   = tid >> 6;
  const int lane = tid & 63;
  const int lg   = lane >> 4;
  const int lr   = lane & 15;
  const int wr   = (wv >> 1) << 6;
  const int wc   = (wv & 1) << 6;

  const int c0 = tid, c1 = tid + 256;
  const size_t gA0 = (size_t)(row0 + (c0>>2))*DMODEL + (size_t)((c0&3)<<3);
  const size_t gA1 = (size_t)(row0 + (c1>>2))*DMODEL + (size_t)((c1&3)<<3);
  const size_t gB0 = (size_t)(col0 + (c0>>2))*DMODEL + (size_t)((c0&3)<<3);
  const size_t gB1 = (size_t)(col0 + (c1>>2))*DMODEL + (size_t)((c1&3)<<3);
  const int wb = (tid >> 6) << 6;
  bf16* lA0 = As + (size_t)wb*8;
  bf16* lA1 = As + (size_t)(wb+256)*8;
  bf16* lB0 = Bs + (size_t)wb*8;
  bf16* lB1 = Bs + (size_t)(wb+256)*8;

  f32x4 acc[4][4];
  #pragma unroll
  for (int mi=0; mi<4; ++mi)
    #pragma unroll
    for (int ni=0; ni<4; ++ni)
      acc[mi][ni] = (f32x4){0.f,0.f,0.f,0.f};

  for (int k0 = 0; k0 < DMODEL; k0 += BK) {
    __syncthreads();
    gload16(X    + gA0 + k0, lA0);
    gload16(X    + gA1 + k0, lA1);
    gload16(Wcat + gB0 + k0, lB0);
    gload16(Wcat + gB1 + k0, lB1);
    __syncthreads();

    bf16x8 af[4], bfr[4];
    #pragma unroll
    for (int mi=0; mi<4; ++mi)
      af[mi] = *(const bf16x8*)&As[(wr + mi*16 + lr)*BK + lg*8];
    #pragma unroll
    for (int ni=0; ni<4; ++ni)
      bfr[ni] = *(const bf16x8*)&Bs[(wc + ni*16 + lr)*BK + lg*8];

    #pragma unroll
    for (int mi=0; mi<4; ++mi)
      #pragma unroll
      for (int ni=0; ni<4; ++ni)
        acc[mi][ni] = __builtin_amdgcn_mfma_f32_16x16x32_bf16(af[mi], bfr[ni], acc[mi][ni], 0, 0, 0);
  }

  const float* bias = (wsel==0) ? bq : ((wsel==1) ? bk : bv);
  bf16* Out = (wsel==0) ? Qo : ((wsel==1) ? Ko : Vo);
  const float oscale = (wsel==0) ? QSCALE : 1.0f;   // fold 0.125*log2e into Q

  #pragma unroll
  for (int ni=0; ni<4; ++ni) {
    const int co = coln + wc + ni*16 + lr;
    const float bias_v = bias[co];
    const int h  = co >> 6;
    const int dh = co & 63;
    #pragma unroll
    for (int mi=0; mi<4; ++mi) {
      #pragma unroll
      for (int p=0; p<4; ++p) {
        const int gr = row0 + wr + mi*16 + lg*4 + p;
        const int s_ = gr >> 2;
        const int b_ = gr & 3;
        Out[((size_t)(b_*NHEAD + h)*S_LEN + s_)*DHEAD + dh] = (bf16)((acc[mi][ni][p] + bias_v) * oscale);
      }
    }
  }
}

// ---------------- MFMA flash attention: r7 body (best measured, ~35us) ----------------
// 4 waves x 32 q-rows, QBLK=128, dbuf K/V (KVB=64), XOR chunk-swizzle, zero-shuffle P,
// swapped QK^T (D[t][q], q=lane&31), f32 additive mask in LDS (exp2 underflow -> 0).
#define QBLK 128
#define LSW(row, chunk) (((row)<<6) + ((((chunk) ^ ((row)&7)))<<3))

__global__ __launch_bounds__(256, 2) void attn_mfma(
    const bf16* __restrict__ Q, const bf16* __restrict__ K, const bf16* __restrict__ V,
    const float* __restrict__ mask, float* __restrict__ out)
{
  __shared__ __align__(16) bf16 Ks[2][64*64];   // 16 KB
  __shared__ __align__(16) bf16 Vt[2][64*64];   // 16 KB (V^T, swizzled)
  __shared__ float Mskf[S_LEN];                 //  4 KB
  __shared__ float Linv[4][32];                 // 512 B

  const int bh   = blockIdx.x;
  const int b_   = bh >> 4;
  const int h_   = bh & 15;
  const int tid  = threadIdx.x;
  const int wv   = tid >> 6;             // 0..3
  const int lane = tid & 63;
  const int l31  = lane & 31;
  const int hh   = lane >> 5;            // 0/1
  const int q0   = blockIdx.y * QBLK;

  // ---- stage mask row (raw f32; -1e4 additive underflows exp2 to 0) ----
  *(float4*)&Mskf[tid*4] = *(const float4*)&mask[(size_t)b_*S_LEN + tid*4];

  // ---- Q B-frags from global (pre-scaled by QSCALE in gemm): q = lane&31 ----
  const bf16* Qp = Q + ((size_t)bh*S_LEN + q0 + wv*32 + l31)*DHEAD;
  bf16x8 qb[4];
  #pragma unroll
  for (int dk=0; dk<4; ++dk) qb[dk] = *(const bf16x8*)&Qp[dk*16 + hh*8];

  const bf16* Kb = K + (size_t)bh*S_LEN*DHEAD;
  const bf16* Vb = V + (size_t)bh*S_LEN*DHEAD;

  // staging maps (256 threads)
  const int krow = tid >> 2, kch = tid & 3;   // K: row, chunks kch & kch+4
  const int vrow = tid & 63, vcb = tid >> 6;  // V: row=lane, 16 cols starting vcb*16

  // ---- prologue: stage tile 0 ----
  bf16x8 kr0 = *(const bf16x8*)&Kb[(size_t)krow*DHEAD + kch*8];
  bf16x8 kr1 = *(const bf16x8*)&Kb[(size_t)krow*DHEAD + kch*8 + 32];
  bf16x8 vr0 = *(const bf16x8*)&Vb[(size_t)vrow*DHEAD + vcb*16];
  bf16x8 vr1 = *(const bf16x8*)&Vb[(size_t)vrow*DHEAD + vcb*16 + 8];
  {
    *(bf16x8*)&Ks[0][LSW(krow, kch)]   = kr0;
    *(bf16x8*)&Ks[0][LSW(krow, kch+4)] = kr1;
    #pragma unroll
    for (int i=0;i<8;++i) {
      const int d0 = vcb*16 + i, d1 = d0 + 8;
      Vt[0][(d0<<6) + (((vrow>>3) ^ (d0&7))<<3) + (vrow&7)] = vr0[i];
      Vt[0][(d1<<6) + (((vrow>>3) ^ (d1&7))<<3) + (vrow&7)] = vr1[i];
    }
  }
  __syncthreads();

  f32x16 ctx[2];
  ctx[0] = (f32x16)0.f; ctx[1] = (f32x16)0.f;
  float lsum = 0.f;

  for (int t = 0; t < 16; ++t) {
    const bf16* Kc = Ks[t & 1];
    const bf16* Vc = Vt[t & 1];

    // issue next tile's global loads early
    if (t < 15) {
      const size_t nb = (size_t)(t+1)*64;
      kr0 = *(const bf16x8*)&Kb[(nb+krow)*DHEAD + kch*8];
      kr1 = *(const bf16x8*)&Kb[(nb+krow)*DHEAD + kch*8 + 32];
      vr0 = *(const bf16x8*)&Vb[(nb+vrow)*DHEAD + vcb*16];
      vr1 = *(const bf16x8*)&Vb[(nb+vrow)*DHEAD + vcb*16 + 8];
    }

    // ---- QK^T (swapped): D[t][q], 2 t-tiles of 32, contraction dh=64 ----
    f32x16 sacc[2];
    sacc[0] = (f32x16)0.f; sacc[1] = (f32x16)0.f;
    __builtin_amdgcn_s_setprio(1);
    #pragma unroll
    for (int tt=0; tt<2; ++tt) {
      const int row = tt*32 + l31;
      #pragma unroll
      for (int dk=0; dk<4; ++dk) {
        bf16x8 ka = *(const bf16x8*)&Kc[LSW(row, dk*2 + hh)];
        sacc[tt] = __builtin_amdgcn_mfma_f32_32x32x16_bf16(ka, qb[dk], sacc[tt], 0,0,0);
      }
    }
    __builtin_amdgcn_s_setprio(0);

    // ---- softmax: p = exp2(s + m); lsum VALU; pack to PV A-frags in-lane ----
    const int tb = t*64;
    bf16x8 pf[2][2];
    #pragma unroll
    for (int tt=0; tt<2; ++tt) {
      f32x4 mv[4];
      #pragma unroll
      for (int g=0; g<4; ++g)
        mv[g] = *(const f32x4*)&Mskf[tb + tt*32 + 8*g + 4*hh];
      float pe[16];
      #pragma unroll
      for (int e=0; e<16; ++e) {
        pe[e] = fast_exp2(sacc[tt][e] + mv[e>>2][e&3]);
        lsum += pe[e];
      }
      union { bf16x2 h2[8]; bf16x8 v[2]; } u;
      #pragma unroll
      for (int j=0; j<8; ++j) { bf16x2 p2; p2[0]=(bf16)pe[2*j]; p2[1]=(bf16)pe[2*j+1]; u.h2[j]=p2; }
      pf[tt][0] = u.v[0]; pf[tt][1] = u.v[1];
    }

    // ---- PV: O[q][d] += P * V ; B-frags via slot->t map (2x b64 each) ----
    __builtin_amdgcn_s_setprio(1);
    #pragma unroll
    for (int nt=0; nt<2; ++nt) {
      const int drow = nt*32 + l31;
      const int dbase = (drow<<6) + 4*hh;
      const int dsw = (drow&7);
      #pragma unroll
      for (int tt=0; tt<2; ++tt) {
        #pragma unroll
        for (int kk=0; kk<2; ++kk) {
          const int lc = tt*4 + kk*2;
          bf16x4 lo = *(const bf16x4*)&Vc[dbase + (((lc  ) ^ dsw)<<3)];
          bf16x4 hi = *(const bf16x4*)&Vc[dbase + (((lc+1) ^ dsw)<<3)];
          bf16x8 vb;
          #pragma unroll
          for (int j=0; j<4; ++j) { vb[j]=lo[j]; vb[4+j]=hi[j]; }
          ctx[nt] = __builtin_amdgcn_mfma_f32_32x32x16_bf16(pf[tt][kk], vb, ctx[nt], 0,0,0);
        }
      }
    }
    __builtin_amdgcn_s_setprio(0);

    // ---- stage next tile into other buffer ----
    if (t < 15) {
      bf16* Kn = (bf16*)Ks[(t+1) & 1];
      bf16* Vn = (bf16*)Vt[(t+1) & 1];
      *(bf16x8*)&Kn[LSW(krow, kch)]   = kr0;
      *(bf16x8*)&Kn[LSW(krow, kch+4)] = kr1;
      #pragma unroll
      for (int i=0;i<8;++i) {
        const int d0 = vcb*16 + i, d1 = d0 + 8;
        Vn[(d0<<6) + (((vrow>>3) ^ (d0&7))<<3) + (vrow&7)] = vr0[i];
        Vn[(d1<<6) + (((vrow>>3) ^ (d1&7))<<3) + (vrow&7)] = vr1[i];
      }
    }
    __syncthreads();
  }

  // ---- lsum: partner-half add, distribute 1/lsum via per-wave LDS row ----
  const float tot = lsum + __shfl_xor(lsum, 32);
  if (lane < 32) Linv[wv][l31] = 1.f / tot;
  f32x4 inv4[4];
  #pragma unroll
  for (int g4=0; g4<4; ++g4) inv4[g4] = *(const f32x4*)&Linv[wv][8*g4 + 4*hh];

  // ---- write out: out[qg][b][h*64 + nt*32 + (lane&31)] ----
  float* op = out + ((size_t)(q0 + wv*32)*BATCH + b_)*DMODEL + h_*DHEAD + l31;
  #pragma unroll
  for (int e=0; e<16; ++e) {
    const int qe = (e&3) + 8*(e>>2) + 4*hh;
    const float inv = inv4[e>>2][e&3];
    float* oq = op + (size_t)qe*BATCH*DMODEL;
    oq[0]  = ctx[0][e] * inv;
    oq[32] = ctx[1][e] * inv;
  }
}

// ---------------- launch ----------------
extern "C" void kernel_launch(void* const* d_in, const int* in_sizes, int n_in,
                              void* d_out, int out_size, void* d_ws, size_t ws_size,
                              hipStream_t stream) {
  const float* hs   = (const float*)d_in[0];
  const float* mask = (const float*)d_in[1];
  const float* Wq   = (const float*)d_in[2];
  const float* bq   = (const float*)d_in[3];
  const float* Wk   = (const float*)d_in[4];
  const float* bk   = (const float*)d_in[5];
  const float* Wv   = (const float*)d_in[6];
  const float* bv   = (const float*)d_in[7];
  float* out = (float*)d_out;

  char* ws = (char*)d_ws;
  bf16* Xb = (bf16*)ws;                               // 8 MB
  bf16* Wb = Xb + (size_t)NROWS*DMODEL;               // 6 MB
  bf16* Qw = Wb + (size_t)3*DMODEL*DMODEL;            // 8 MB
  bf16* Kw = Qw + (size_t)NROWS*DMODEL;               // 8 MB
  bf16* Vw = Kw + (size_t)NROWS*DMODEL;               // 8 MB

  cvt_all<<<3584, 256, 0, stream>>>(hs, Wq, Wk, Wv, Xb, Wb);

  qkv_gemm<<<dim3(NROWS/BM, 3*DMODEL/BN), 256, 0, stream>>>(Xb, Wb, bq, bk, bv, Qw, Kw, Vw);

  attn_mfma<<<dim3(BATCH*NHEAD, S_LEN/QBLK), 256, 0, stream>>>(Qw, Kw, Vw, mask, out);
}